// Round 1
// baseline (5668.396 us; speedup 1.0000x reference)
//
#include <hip/hip_runtime.h>

static constexpr float BN_EPS = 1e-5f;

// ---------------------------------------------------------------------------
// Edge scatter: acc[dst] += relu(xin[src] + (a*lin_w + lin_b)), 32 lanes/edge.
// acc must be pre-initialized with the residual term (x or x1).
// ---------------------------------------------------------------------------
__global__ __launch_bounds__(256) void edge_scatter(
    const float* __restrict__ xin, const float* __restrict__ ea,
    const int* __restrict__ src, const int* __restrict__ dst,
    const float* __restrict__ lw, const float* __restrict__ lb,
    float* __restrict__ acc, int E)
{
    const int lane = threadIdx.x & 31;                       // dim group: 4*lane
    int slot = (int)((blockIdx.x * blockDim.x + threadIdx.x) >> 5);
    const int nslots = (int)((gridDim.x * blockDim.x) >> 5);
    const float4 lw4 = ((const float4*)lw)[lane];
    const float4 lb4 = ((const float4*)lb)[lane];
    for (int j = slot; j < E; j += nslots) {
        const float a = ea[j];
        const int s = src[j];
        const int d = dst[j];
        const float4 x4 = ((const float4*)(xin + (size_t)s * 128))[lane];
        const float m0 = fmaxf(fmaf(a, lw4.x, lb4.x) + x4.x, 0.f);
        const float m1 = fmaxf(fmaf(a, lw4.y, lb4.y) + x4.y, 0.f);
        const float m2 = fmaxf(fmaf(a, lw4.z, lb4.z) + x4.z, 0.f);
        const float m3 = fmaxf(fmaf(a, lw4.w, lb4.w) + x4.w, 0.f);
        float* p = acc + (size_t)d * 128 + lane * 4;
        unsafeAtomicAdd(p + 0, m0);
        unsafeAtomicAdd(p + 1, m1);
        unsafeAtomicAdd(p + 2, m2);
        unsafeAtomicAdd(p + 3, m3);
    }
}

// ---------------------------------------------------------------------------
// Fused GEMM + bias + relu.  Y[n,m] = relu(sum_k A[n,k] W[k,m] + b[m]).
// A can be split at column KS between A1 (stride KS) and A2 (stride K-KS)
// to implement concat without materializing it. Block tile: R=BY*TR rows x M
// cols, per-thread TR rows x 4 cols. W staged in K-chunks of 32 in LDS, A
// staged transposed (As[k][row]) for vector reads.
// ---------------------------------------------------------------------------
template<int K, int KS, int M, int BY, int TR>
__global__ __launch_bounds__((M / 4) * BY) void gemm_relu(
    const float* __restrict__ A1, const float* __restrict__ A2,
    const float* __restrict__ W, const float* __restrict__ bias,
    float* __restrict__ Y, int N)
{
    constexpr int BX = M / 4;
    constexpr int NT = BX * BY;
    constexpr int R  = BY * TR;        // rows per block (64)
    constexpr int KC = 32;             // K chunk
    constexpr int AST = R + 4;         // padded A stride (68 floats, 16B-mult)
    __shared__ float Ws[KC * M];
    __shared__ float As[KC * AST];
    const int tx = threadIdx.x, ty = threadIdx.y;
    const int tid = ty * BX + tx;
    const int row0 = blockIdx.x * R;

    float acc[TR][4];
#pragma unroll
    for (int r = 0; r < TR; ++r) { acc[r][0] = acc[r][1] = acc[r][2] = acc[r][3] = 0.f; }

    for (int kc = 0; kc < K; kc += KC) {
        __syncthreads();
        for (int i = tid; i < KC * M / 4; i += NT)
            ((float4*)Ws)[i] = ((const float4*)(W + (size_t)kc * M))[i];
        for (int i = tid; i < R * KC / 4; i += NT) {
            const int r  = i / (KC / 4);
            const int k4 = i % (KC / 4);
            int row = row0 + r; if (row >= N) row = N - 1;  // clamp (stores guarded)
            const int kg = kc + k4 * 4;
            float4 v;
            if constexpr (KS < K) {
                if (kg >= KS) v = *(const float4*)(A2 + (size_t)row * (K - KS) + (kg - KS));
                else          v = *(const float4*)(A1 + (size_t)row * KS + kg);
            } else {
                v = *(const float4*)(A1 + (size_t)row * K + kg);
            }
            As[(k4 * 4 + 0) * AST + r] = v.x;
            As[(k4 * 4 + 1) * AST + r] = v.y;
            As[(k4 * 4 + 2) * AST + r] = v.z;
            As[(k4 * 4 + 3) * AST + r] = v.w;
        }
        __syncthreads();
#pragma unroll 8
        for (int kk = 0; kk < KC; ++kk) {
            const float4 w4 = *(const float4*)&Ws[kk * M + tx * 4];
            float a[TR];
            if constexpr (TR % 4 == 0) {
#pragma unroll
                for (int q = 0; q < TR / 4; ++q) {
                    const float4 av = *(const float4*)&As[kk * AST + ty * TR + q * 4];
                    a[q * 4 + 0] = av.x; a[q * 4 + 1] = av.y;
                    a[q * 4 + 2] = av.z; a[q * 4 + 3] = av.w;
                }
            } else {
#pragma unroll
                for (int r = 0; r < TR; ++r) a[r] = As[kk * AST + ty * TR + r];
            }
#pragma unroll
            for (int r = 0; r < TR; ++r) {
                acc[r][0] = fmaf(a[r], w4.x, acc[r][0]);
                acc[r][1] = fmaf(a[r], w4.y, acc[r][1]);
                acc[r][2] = fmaf(a[r], w4.z, acc[r][2]);
                acc[r][3] = fmaf(a[r], w4.w, acc[r][3]);
            }
        }
    }
    const float4 b4 = ((const float4*)bias)[tx];
#pragma unroll
    for (int r = 0; r < TR; ++r) {
        const int row = row0 + ty * TR + r;
        if (row < N) {
            float4 o;
            o.x = fmaxf(acc[r][0] + b4.x, 0.f);
            o.y = fmaxf(acc[r][1] + b4.y, 0.f);
            o.z = fmaxf(acc[r][2] + b4.z, 0.f);
            o.w = fmaxf(acc[r][3] + b4.w, 0.f);
            ((float4*)(Y + (size_t)row * M))[tx] = o;
        }
    }
}

// ---------------------------------------------------------------------------
// Per-column sum / sum-of-squares over [N, M] (stride M, first MR cols real).
// ---------------------------------------------------------------------------
template<int M, int MR, int BY>
__global__ __launch_bounds__(M * BY) void colstats(
    const float* __restrict__ Y, float* __restrict__ sum, float* __restrict__ sq, int N)
{
    __shared__ float ss[BY][M];
    __shared__ float sQ[BY][M];
    const int tx = threadIdx.x, ty = threadIdx.y;
    float s = 0.f, q = 0.f;
    for (int r = blockIdx.x * BY + ty; r < N; r += gridDim.x * BY) {
        const float v = Y[(size_t)r * M + tx];
        s += v; q = fmaf(v, v, q);
    }
    ss[ty][tx] = s; sQ[ty][tx] = q;
    __syncthreads();
    if (ty == 0 && tx < MR) {
#pragma unroll
        for (int t = 1; t < BY; ++t) { s += ss[t][tx]; q += sQ[t][tx]; }
        unsafeAtomicAdd(&sum[tx], s);
        unsafeAtomicAdd(&sq[tx], q);
    }
}

template<int M>
__global__ void bn_finalize(const float* __restrict__ sum, const float* __restrict__ sq,
                            const float* __restrict__ g, const float* __restrict__ be,
                            float* __restrict__ scale, float* __restrict__ shift, float invN)
{
    const int i = threadIdx.x;
    if (i < M) {
        const float m = sum[i] * invN;
        const float v = sq[i] * invN - m * m;     // biased variance
        const float sc = g[i] * rsqrtf(v + BN_EPS);
        scale[i] = sc;
        shift[i] = be[i] - m * sc;
    }
}

template<int M>
__global__ __launch_bounds__(256) void bn_apply(
    float* __restrict__ Y, const float* __restrict__ scale,
    const float* __restrict__ shift, int total4)
{
    for (int i = blockIdx.x * 256 + threadIdx.x; i < total4; i += gridDim.x * 256) {
        const int c = i % (M / 4);
        float4 v = ((float4*)Y)[i];
        const float4 sc = ((const float4*)scale)[c];
        const float4 sh = ((const float4*)shift)[c];
        v.x = fmaf(v.x, sc.x, sh.x);
        v.y = fmaf(v.y, sc.y, sh.y);
        v.z = fmaf(v.z, sc.z, sh.z);
        v.w = fmaf(v.w, sc.w, sh.w);
        ((float4*)Y)[i] = v;
    }
}

__global__ __launch_bounds__(256) void bn_apply_final(
    const float* __restrict__ Y16, const float* __restrict__ scale,
    const float* __restrict__ shift, float* __restrict__ out, int total)
{
    for (int i = blockIdx.x * 256 + threadIdx.x; i < total; i += gridDim.x * 256) {
        const int n = i / 10;
        const int c = i - n * 10;
        out[i] = fmaf(Y16[(size_t)n * 16 + c], scale[c], shift[c]);
    }
}

// pad w5 [96,10] -> [96,16], b5 [10] -> [16] (zero pad)
__global__ __launch_bounds__(256) void pad_w5(
    const float* __restrict__ w5, const float* __restrict__ b5,
    float* __restrict__ w5p, float* __restrict__ b5p)
{
    const int i = blockIdx.x * 256 + threadIdx.x;
    if (i < 96 * 16) {
        const int k = i >> 4, c = i & 15;
        w5p[i] = (c < 10) ? w5[k * 10 + c] : 0.f;
    } else if (i < 96 * 16 + 16) {
        const int c = i - 96 * 16;
        b5p[c] = (c < 10) ? b5[c] : 0.f;
    }
}

// ---------------------------------------------------------------------------
extern "C" void kernel_launch(void* const* d_in, const int* in_sizes, int n_in,
                              void* d_out, int out_size, void* d_ws, size_t ws_size,
                              hipStream_t stream)
{
    const float* x   = (const float*)d_in[0];
    const float* ea  = (const float*)d_in[1];
    const int*   ei  = (const int*)d_in[2];
    const float* lw  = (const float*)d_in[3];
    const float* lb  = (const float*)d_in[4];
    const float* w1  = (const float*)d_in[5];
    const float* b1  = (const float*)d_in[6];
    const float* g1  = (const float*)d_in[7];
    const float* be1 = (const float*)d_in[8];
    const float* w2  = (const float*)d_in[9];
    const float* b2  = (const float*)d_in[10];
    const float* g2  = (const float*)d_in[11];
    const float* be2 = (const float*)d_in[12];
    const float* w3  = (const float*)d_in[13];
    const float* b3  = (const float*)d_in[14];
    const float* g3  = (const float*)d_in[15];
    const float* be3 = (const float*)d_in[16];
    const float* w4  = (const float*)d_in[17];
    const float* b4  = (const float*)d_in[18];
    const float* g4  = (const float*)d_in[19];
    const float* be4 = (const float*)d_in[20];
    const float* w5  = (const float*)d_in[21];
    const float* b5  = (const float*)d_in[22];
    const float* g5  = (const float*)d_in[23];
    const float* be5 = (const float*)d_in[24];

    const int N = in_sizes[0] / 128;   // 50000
    const int E = in_sizes[1];         // 1600000
    const int* src = ei;
    const int* dst = ei + E;
    const float invN = 1.0f / (float)N;

    float* ws = (float*)d_ws;
    float* bufA = ws;                          // N*128  (t1, t2, y3/h3)
    float* bufB = ws + (size_t)N * 128;        // N*128  (y1/x1, y4/h4)
    float* bufC = ws + (size_t)N * 256;        // N*64   (y2/x2, y5[N,16])
    float* smallr = ws + (size_t)N * 320;
    float* sums   = smallr;                    // 10 slots of 128 (sum_l, sq_l)
    float* scales = smallr + 1280;             // 5 slots of 128
    float* shifts = smallr + 1920;             // 5 slots of 128
    float* w5p    = smallr + 2560;             // 96*16
    float* b5p    = w5p + 1536;                // 16
#define SUM(l)   (sums + (l) * 128)
#define SQ(l)    (sums + (5 + (l)) * 128)
#define SCALE(l) (scales + (l) * 128)
#define SHIFT(l) (shifts + (l) * 128)

    hipMemsetAsync(sums, 0, 1280 * sizeof(float), stream);
    pad_w5<<<7, 256, 0, stream>>>(w5, b5, w5p, b5p);

    const int gemmGrid = (N + 63) / 64;

    // ---- conv1: t1 = x + sum relu(x[src]+e); x1 = BN(relu(t1 @ w1 + b1))
    hipMemcpyAsync(bufA, x, (size_t)N * 128 * 4, hipMemcpyDeviceToDevice, stream);
    edge_scatter<<<8192, 256, 0, stream>>>(x, ea, src, dst, lw, lb, bufA, E);
    gemm_relu<128, 128, 128, 8, 8><<<gemmGrid, dim3(32, 8), 0, stream>>>(bufA, nullptr, w1, b1, bufB, N);
    colstats<128, 128, 2><<<512, dim3(128, 2), 0, stream>>>(bufB, SUM(0), SQ(0), N);
    bn_finalize<128><<<1, 128, 0, stream>>>(SUM(0), SQ(0), g1, be1, SCALE(0), SHIFT(0), invN);
    bn_apply<128><<<2048, 256, 0, stream>>>(bufB, SCALE(0), SHIFT(0), N * 32);

    // ---- conv2: t2 = x1 + sum relu(x1[src]+e); x2 = BN(relu(t2 @ w2 + b2))
    hipMemcpyAsync(bufA, bufB, (size_t)N * 128 * 4, hipMemcpyDeviceToDevice, stream);
    edge_scatter<<<8192, 256, 0, stream>>>(bufB, ea, src, dst, lw, lb, bufA, E);
    gemm_relu<128, 128, 64, 16, 4><<<gemmGrid, dim3(16, 16), 0, stream>>>(bufA, nullptr, w2, b2, bufC, N);
    colstats<64, 64, 4><<<512, dim3(64, 4), 0, stream>>>(bufC, SUM(1), SQ(1), N);
    bn_finalize<64><<<1, 128, 0, stream>>>(SUM(1), SQ(1), g2, be2, SCALE(1), SHIFT(1), invN);
    bn_apply<64><<<2048, 256, 0, stream>>>(bufC, SCALE(1), SHIFT(1), N * 16);

    // ---- lin1: h3 = BN(relu(concat(x1,x2) @ w3 + b3))   (K split 128|64)
    gemm_relu<192, 128, 96, 8, 8><<<gemmGrid, dim3(24, 8), 0, stream>>>(bufB, bufC, w3, b3, bufA, N);
    colstats<96, 96, 2><<<512, dim3(96, 2), 0, stream>>>(bufA, SUM(2), SQ(2), N);
    bn_finalize<96><<<1, 128, 0, stream>>>(SUM(2), SQ(2), g3, be3, SCALE(2), SHIFT(2), invN);
    bn_apply<96><<<2048, 256, 0, stream>>>(bufA, SCALE(2), SHIFT(2), N * 24);

    // ---- mlp1 layer 1: h4 = BN(relu(h3 @ w4 + b4))
    gemm_relu<96, 96, 96, 8, 8><<<gemmGrid, dim3(24, 8), 0, stream>>>(bufA, nullptr, w4, b4, bufB, N);
    colstats<96, 96, 2><<<512, dim3(96, 2), 0, stream>>>(bufB, SUM(3), SQ(3), N);
    bn_finalize<96><<<1, 128, 0, stream>>>(SUM(3), SQ(3), g4, be4, SCALE(3), SHIFT(3), invN);
    bn_apply<96><<<2048, 256, 0, stream>>>(bufB, SCALE(3), SHIFT(3), N * 24);

    // ---- mlp1 layer 2: out = BN(relu(h4 @ w5 + b5))  (M padded 10->16)
    gemm_relu<96, 96, 16, 64, 1><<<gemmGrid, dim3(4, 64), 0, stream>>>(bufB, nullptr, w5p, b5p, bufC, N);
    colstats<16, 10, 16><<<512, dim3(16, 16), 0, stream>>>(bufC, SUM(4), SQ(4), N);
    bn_finalize<10><<<1, 128, 0, stream>>>(SUM(4), SQ(4), g5, be5, SCALE(4), SHIFT(4), invN);
    bn_apply_final<<<1024, 256, 0, stream>>>(bufC, SCALE(4), SHIFT(4), (float*)d_out, N * 10);
#undef SUM
#undef SQ
#undef SCALE
#undef SHIFT
}

// Round 2
// 847.824 us; speedup vs baseline: 6.6858x; 6.6858x over previous
//
#include <hip/hip_runtime.h>

static constexpr float BN_EPS = 1e-5f;

// ---------------------------------------------------------------------------
// CSR build: counting sort of edges by dst.
// ---------------------------------------------------------------------------
__global__ __launch_bounds__(256) void count_dst(
    const int* __restrict__ dst, int* __restrict__ cnt, int E)
{
    int i = blockIdx.x * 256 + threadIdx.x;
    const int stride = gridDim.x * 256;
    for (; i < E; i += stride) atomicAdd(&cnt[dst[i]], 1);
}

__device__ inline int wave_incl_scan(int v, int lane)
{
#pragma unroll
    for (int s = 1; s < 64; s <<= 1) {
        const int t = __shfl_up(v, s, 64);
        if (lane >= s) v += t;
    }
    return v;
}

// single-block exclusive scan over n counters -> off[0..n], head copy
__global__ __launch_bounds__(1024) void scan_off(
    const int* __restrict__ cnt, int* __restrict__ off, int* __restrict__ head, int n)
{
    __shared__ int wsum[16];
    __shared__ int carry;
    const int tid = threadIdx.x;
    const int lane = tid & 63, wid = tid >> 6;
    if (tid == 0) carry = 0;
    __syncthreads();
    for (int base = 0; base < n; base += 1024) {
        const int v = (base + tid < n) ? cnt[base + tid] : 0;
        int incl = wave_incl_scan(v, lane);
        if (lane == 63) wsum[wid] = incl;
        __syncthreads();
        if (wid == 0) {
            int wv = (lane < 16) ? wsum[lane] : 0;
            wv = wave_incl_scan(wv, lane);
            if (lane < 16) wsum[lane] = wv;
        }
        __syncthreads();
        const int waveoff = (wid > 0) ? wsum[wid - 1] : 0;
        const int total = wsum[15];
        const int c = carry;
        const int excl = c + waveoff + incl - v;
        if (base + tid < n) { off[base + tid] = excl; head[base + tid] = excl; }
        __syncthreads();
        if (tid == 0) carry = c + total;
        __syncthreads();
    }
    if (tid == 0) off[n] = carry;
}

__global__ __launch_bounds__(256) void fill_csr(
    const int* __restrict__ src, const int* __restrict__ dst,
    const float* __restrict__ ea, int* __restrict__ head,
    int* __restrict__ srcS, float* __restrict__ eaS, int E)
{
    int i = blockIdx.x * 256 + threadIdx.x;
    const int stride = gridDim.x * 256;
    for (; i < E; i += stride) {
        const int pos = atomicAdd(&head[dst[i]], 1);
        srcS[pos] = src[i];
        eaS[pos] = ea[i];
    }
}

// ---------------------------------------------------------------------------
// GINE aggregation, CSR form: one wave per node, float2 per lane (128 cols).
// acc[node] = xin[node] + sum_p relu(xin[srcS[p]] + eaS[p]*lw + lb)
// ---------------------------------------------------------------------------
__global__ __launch_bounds__(256) void gine_aggr(
    const float* __restrict__ xin, const int* __restrict__ off,
    const int* __restrict__ srcS, const float* __restrict__ eaS,
    const float* __restrict__ lw, const float* __restrict__ lb,
    float* __restrict__ acc, int N)
{
    const int lane = threadIdx.x & 63;
    const int node = blockIdx.x * 4 + (threadIdx.x >> 6);
    if (node >= N) return;
    const float2 lw2 = ((const float2*)lw)[lane];
    const float2 lb2 = ((const float2*)lb)[lane];
    const int pbeg = off[node], pend = off[node + 1];
    float2 s = ((const float2*)(xin + (size_t)node * 128))[lane];
    for (int p = pbeg; p < pend; ++p) {
        const int si = srcS[p];
        const float a = eaS[p];
        const float2 xv = ((const float2*)(xin + (size_t)si * 128))[lane];
        s.x += fmaxf(fmaf(a, lw2.x, lb2.x) + xv.x, 0.f);
        s.y += fmaxf(fmaf(a, lw2.y, lb2.y) + xv.y, 0.f);
    }
    ((float2*)(acc + (size_t)node * 128))[lane] = s;
}

// ---------------------------------------------------------------------------
// Fused GEMM + bias + relu.  Y[n,m] = relu(sum_k A[n,k] W[k,m] + b[m]).
// A can be split at column KS between A1 (stride KS) and A2 (stride K-KS).
// ---------------------------------------------------------------------------
template<int K, int KS, int M, int BY, int TR>
__global__ __launch_bounds__((M / 4) * BY) void gemm_relu(
    const float* __restrict__ A1, const float* __restrict__ A2,
    const float* __restrict__ W, const float* __restrict__ bias,
    float* __restrict__ Y, int N)
{
    constexpr int BX = M / 4;
    constexpr int NT = BX * BY;
    constexpr int R  = BY * TR;        // rows per block (64)
    constexpr int KC = 32;             // K chunk
    constexpr int AST = R + 4;
    __shared__ float Ws[KC * M];
    __shared__ float As[KC * AST];
    const int tx = threadIdx.x, ty = threadIdx.y;
    const int tid = ty * BX + tx;
    const int row0 = blockIdx.x * R;

    float acc[TR][4];
#pragma unroll
    for (int r = 0; r < TR; ++r) { acc[r][0] = acc[r][1] = acc[r][2] = acc[r][3] = 0.f; }

    for (int kc = 0; kc < K; kc += KC) {
        __syncthreads();
        for (int i = tid; i < KC * M / 4; i += NT)
            ((float4*)Ws)[i] = ((const float4*)(W + (size_t)kc * M))[i];
        for (int i = tid; i < R * KC / 4; i += NT) {
            const int r  = i / (KC / 4);
            const int k4 = i % (KC / 4);
            int row = row0 + r; if (row >= N) row = N - 1;
            const int kg = kc + k4 * 4;
            float4 v;
            if constexpr (KS < K) {
                if (kg >= KS) v = *(const float4*)(A2 + (size_t)row * (K - KS) + (kg - KS));
                else          v = *(const float4*)(A1 + (size_t)row * KS + kg);
            } else {
                v = *(const float4*)(A1 + (size_t)row * K + kg);
            }
            As[(k4 * 4 + 0) * AST + r] = v.x;
            As[(k4 * 4 + 1) * AST + r] = v.y;
            As[(k4 * 4 + 2) * AST + r] = v.z;
            As[(k4 * 4 + 3) * AST + r] = v.w;
        }
        __syncthreads();
#pragma unroll 8
        for (int kk = 0; kk < KC; ++kk) {
            const float4 w4 = *(const float4*)&Ws[kk * M + tx * 4];
            float a[TR];
            if constexpr (TR % 4 == 0) {
#pragma unroll
                for (int q = 0; q < TR / 4; ++q) {
                    const float4 av = *(const float4*)&As[kk * AST + ty * TR + q * 4];
                    a[q * 4 + 0] = av.x; a[q * 4 + 1] = av.y;
                    a[q * 4 + 2] = av.z; a[q * 4 + 3] = av.w;
                }
            } else {
#pragma unroll
                for (int r = 0; r < TR; ++r) a[r] = As[kk * AST + ty * TR + r];
            }
#pragma unroll
            for (int r = 0; r < TR; ++r) {
                acc[r][0] = fmaf(a[r], w4.x, acc[r][0]);
                acc[r][1] = fmaf(a[r], w4.y, acc[r][1]);
                acc[r][2] = fmaf(a[r], w4.z, acc[r][2]);
                acc[r][3] = fmaf(a[r], w4.w, acc[r][3]);
            }
        }
    }
    const float4 b4 = ((const float4*)bias)[tx];
#pragma unroll
    for (int r = 0; r < TR; ++r) {
        const int row = row0 + ty * TR + r;
        if (row < N) {
            float4 o;
            o.x = fmaxf(acc[r][0] + b4.x, 0.f);
            o.y = fmaxf(acc[r][1] + b4.y, 0.f);
            o.z = fmaxf(acc[r][2] + b4.z, 0.f);
            o.w = fmaxf(acc[r][3] + b4.w, 0.f);
            ((float4*)(Y + (size_t)row * M))[tx] = o;
        }
    }
}

// ---------------------------------------------------------------------------
// Per-column sum / sum-of-squares over [N, M] (stride M, first MR cols real).
// ---------------------------------------------------------------------------
template<int M, int MR, int BY>
__global__ __launch_bounds__(M * BY) void colstats(
    const float* __restrict__ Y, float* __restrict__ sum, float* __restrict__ sq, int N)
{
    __shared__ float ss[BY][M];
    __shared__ float sQ[BY][M];
    const int tx = threadIdx.x, ty = threadIdx.y;
    float s = 0.f, q = 0.f;
    for (int r = blockIdx.x * BY + ty; r < N; r += gridDim.x * BY) {
        const float v = Y[(size_t)r * M + tx];
        s += v; q = fmaf(v, v, q);
    }
    ss[ty][tx] = s; sQ[ty][tx] = q;
    __syncthreads();
    if (ty == 0 && tx < MR) {
#pragma unroll
        for (int t = 1; t < BY; ++t) { s += ss[t][tx]; q += sQ[t][tx]; }
        unsafeAtomicAdd(&sum[tx], s);
        unsafeAtomicAdd(&sq[tx], q);
    }
}

template<int M>
__global__ void bn_finalize(const float* __restrict__ sum, const float* __restrict__ sq,
                            const float* __restrict__ g, const float* __restrict__ be,
                            float* __restrict__ scale, float* __restrict__ shift, float invN)
{
    const int i = threadIdx.x;
    if (i < M) {
        const float m = sum[i] * invN;
        const float v = sq[i] * invN - m * m;
        const float sc = g[i] * rsqrtf(v + BN_EPS);
        scale[i] = sc;
        shift[i] = be[i] - m * sc;
    }
}

template<int M>
__global__ __launch_bounds__(256) void bn_apply(
    float* __restrict__ Y, const float* __restrict__ scale,
    const float* __restrict__ shift, int total4)
{
    for (int i = blockIdx.x * 256 + threadIdx.x; i < total4; i += gridDim.x * 256) {
        const int c = i % (M / 4);
        float4 v = ((float4*)Y)[i];
        const float4 sc = ((const float4*)scale)[c];
        const float4 sh = ((const float4*)shift)[c];
        v.x = fmaf(v.x, sc.x, sh.x);
        v.y = fmaf(v.y, sc.y, sh.y);
        v.z = fmaf(v.z, sc.z, sh.z);
        v.w = fmaf(v.w, sc.w, sh.w);
        ((float4*)Y)[i] = v;
    }
}

__global__ __launch_bounds__(256) void bn_apply_final(
    const float* __restrict__ Y16, const float* __restrict__ scale,
    const float* __restrict__ shift, float* __restrict__ out, int total)
{
    for (int i = blockIdx.x * 256 + threadIdx.x; i < total; i += gridDim.x * 256) {
        const int n = i / 10;
        const int c = i - n * 10;
        out[i] = fmaf(Y16[(size_t)n * 16 + c], scale[c], shift[c]);
    }
}

// pad w5 [96,10] -> [96,16], b5 [10] -> [16]
__global__ __launch_bounds__(256) void pad_w5(
    const float* __restrict__ w5, const float* __restrict__ b5,
    float* __restrict__ w5p, float* __restrict__ b5p)
{
    const int i = blockIdx.x * 256 + threadIdx.x;
    if (i < 96 * 16) {
        const int k = i >> 4, c = i & 15;
        w5p[i] = (c < 10) ? w5[k * 10 + c] : 0.f;
    } else if (i < 96 * 16 + 16) {
        const int c = i - 96 * 16;
        b5p[c] = (c < 10) ? b5[c] : 0.f;
    }
}

// ---------------------------------------------------------------------------
extern "C" void kernel_launch(void* const* d_in, const int* in_sizes, int n_in,
                              void* d_out, int out_size, void* d_ws, size_t ws_size,
                              hipStream_t stream)
{
    const float* x   = (const float*)d_in[0];
    const float* ea  = (const float*)d_in[1];
    const int*   ei  = (const int*)d_in[2];
    const float* lw  = (const float*)d_in[3];
    const float* lb  = (const float*)d_in[4];
    const float* w1  = (const float*)d_in[5];
    const float* b1  = (const float*)d_in[6];
    const float* g1  = (const float*)d_in[7];
    const float* be1 = (const float*)d_in[8];
    const float* w2  = (const float*)d_in[9];
    const float* b2  = (const float*)d_in[10];
    const float* g2  = (const float*)d_in[11];
    const float* be2 = (const float*)d_in[12];
    const float* w3  = (const float*)d_in[13];
    const float* b3  = (const float*)d_in[14];
    const float* g3  = (const float*)d_in[15];
    const float* be3 = (const float*)d_in[16];
    const float* w4  = (const float*)d_in[17];
    const float* b4  = (const float*)d_in[18];
    const float* g4  = (const float*)d_in[19];
    const float* be4 = (const float*)d_in[20];
    const float* w5  = (const float*)d_in[21];
    const float* b5  = (const float*)d_in[22];
    const float* g5  = (const float*)d_in[23];
    const float* be5 = (const float*)d_in[24];

    const int N = in_sizes[0] / 128;   // 50000
    const int E = in_sizes[1];         // 1600000
    const int* src = ei;
    const int* dst = ei + E;
    const float invN = 1.0f / (float)N;

    float* ws = (float*)d_ws;
    float* bufA = ws;                          // N*128  (t1, t2, y3/h3)
    float* bufB = ws + (size_t)N * 128;        // N*128  (y1/x1, y4/h4)
    float* bufC = ws + (size_t)N * 256;        // N*64   (y2/x2, y5[N,16])
    float* smallr = ws + (size_t)N * 320;      // 8192 floats of small scratch
    float* sums   = smallr;                    // 10 slots of 128 (sum_l, sq_l)
    float* scales = smallr + 1280;             // 5 slots of 128
    float* shifts = smallr + 1920;             // 5 slots of 128
    float* w5p    = smallr + 2560;             // 96*16
    float* b5p    = w5p + 1536;                // 16
    // CSR region
    int*   cnt  = (int*)(ws + (size_t)N * 320 + 8192);
    int*   off  = cnt + 50048;                 // N+1
    int*   head = off + 50048;
    int*   srcS = head + 50048;                // E
    float* eaS  = (float*)(srcS + E);          // E
#define SUM(l)   (sums + (l) * 128)
#define SQ(l)    (sums + (5 + (l)) * 128)
#define SCALE(l) (scales + (l) * 128)
#define SHIFT(l) (shifts + (l) * 128)

    hipMemsetAsync(sums, 0, 1280 * sizeof(float), stream);
    hipMemsetAsync(cnt, 0, (size_t)N * sizeof(int), stream);
    pad_w5<<<7, 256, 0, stream>>>(w5, b5, w5p, b5p);

    // ---- CSR build (reused by both convs)
    count_dst<<<2048, 256, 0, stream>>>(dst, cnt, E);
    scan_off<<<1, 1024, 0, stream>>>(cnt, off, head, N);
    fill_csr<<<2048, 256, 0, stream>>>(src, dst, ea, head, srcS, eaS, E);

    const int gemmGrid = (N + 63) / 64;
    const int aggrGrid = (N + 3) / 4;

    // ---- conv1: t1 = x + sum relu(x[src]+e); x1 = BN(relu(t1 @ w1 + b1))
    gine_aggr<<<aggrGrid, 256, 0, stream>>>(x, off, srcS, eaS, lw, lb, bufA, N);
    gemm_relu<128, 128, 128, 8, 8><<<gemmGrid, dim3(32, 8), 0, stream>>>(bufA, nullptr, w1, b1, bufB, N);
    colstats<128, 128, 2><<<512, dim3(128, 2), 0, stream>>>(bufB, SUM(0), SQ(0), N);
    bn_finalize<128><<<1, 128, 0, stream>>>(SUM(0), SQ(0), g1, be1, SCALE(0), SHIFT(0), invN);
    bn_apply<128><<<2048, 256, 0, stream>>>(bufB, SCALE(0), SHIFT(0), N * 32);

    // ---- conv2: t2 = x1 + sum relu(x1[src]+e); x2 = BN(relu(t2 @ w2 + b2))
    gine_aggr<<<aggrGrid, 256, 0, stream>>>(bufB, off, srcS, eaS, lw, lb, bufA, N);
    gemm_relu<128, 128, 64, 16, 4><<<gemmGrid, dim3(16, 16), 0, stream>>>(bufA, nullptr, w2, b2, bufC, N);
    colstats<64, 64, 4><<<512, dim3(64, 4), 0, stream>>>(bufC, SUM(1), SQ(1), N);
    bn_finalize<64><<<1, 128, 0, stream>>>(SUM(1), SQ(1), g2, be2, SCALE(1), SHIFT(1), invN);
    bn_apply<64><<<2048, 256, 0, stream>>>(bufC, SCALE(1), SHIFT(1), N * 16);

    // ---- lin1: h3 = BN(relu(concat(x1,x2) @ w3 + b3))   (K split 128|64)
    gemm_relu<192, 128, 96, 8, 8><<<gemmGrid, dim3(24, 8), 0, stream>>>(bufB, bufC, w3, b3, bufA, N);
    colstats<96, 96, 2><<<512, dim3(96, 2), 0, stream>>>(bufA, SUM(2), SQ(2), N);
    bn_finalize<96><<<1, 128, 0, stream>>>(SUM(2), SQ(2), g3, be3, SCALE(2), SHIFT(2), invN);
    bn_apply<96><<<2048, 256, 0, stream>>>(bufA, SCALE(2), SHIFT(2), N * 24);

    // ---- mlp1 layer 1: h4 = BN(relu(h3 @ w4 + b4))
    gemm_relu<96, 96, 96, 8, 8><<<gemmGrid, dim3(24, 8), 0, stream>>>(bufA, nullptr, w4, b4, bufB, N);
    colstats<96, 96, 2><<<512, dim3(96, 2), 0, stream>>>(bufB, SUM(3), SQ(3), N);
    bn_finalize<96><<<1, 128, 0, stream>>>(SUM(3), SQ(3), g4, be4, SCALE(3), SHIFT(3), invN);
    bn_apply<96><<<2048, 256, 0, stream>>>(bufB, SCALE(3), SHIFT(3), N * 24);

    // ---- mlp1 layer 2: out = BN(relu(h4 @ w5 + b5))  (M padded 10->16)
    gemm_relu<96, 96, 16, 64, 1><<<gemmGrid, dim3(4, 64), 0, stream>>>(bufB, nullptr, w5p, b5p, bufC, N);
    colstats<16, 10, 16><<<512, dim3(16, 16), 0, stream>>>(bufC, SUM(4), SQ(4), N);
    bn_finalize<10><<<1, 128, 0, stream>>>(SUM(4), SQ(4), g5, be5, SCALE(4), SHIFT(4), invN);
    bn_apply_final<<<1024, 256, 0, stream>>>(bufC, SCALE(4), SHIFT(4), (float*)d_out, N * 10);
#undef SUM
#undef SQ
#undef SCALE
#undef SHIFT
}

// Round 4
// 594.976 us; speedup vs baseline: 9.5271x; 1.4250x over previous
//
#include <hip/hip_runtime.h>
#include <hip/hip_fp16.h>

static constexpr float BN_EPS = 1e-5f;

__device__ __forceinline__ ushort f2h(float f) {
    return __half_as_ushort(__float2half(f));           // RNE
}
__device__ __forceinline__ float2 h2f2(uint u) {
    __half2 h = *reinterpret_cast<__half2*>(&u);
    return __half22float2(h);
}

// ---------------------------------------------------------------------------
// fp32 -> fp16 bulk convert (vectorized, grid-stride)
// ---------------------------------------------------------------------------
__global__ __launch_bounds__(256) void cvt_f16(
    const float* __restrict__ in, ushort* __restrict__ out, int n4)
{
    int i = blockIdx.x * 256 + threadIdx.x;
    const int stride = gridDim.x * 256;
    for (; i < n4; i += stride) {
        const float4 v = ((const float4*)in)[i];
        ushort4 u;
        u.x = f2h(v.x); u.y = f2h(v.y); u.z = f2h(v.z); u.w = f2h(v.w);
        ((ushort4*)out)[i] = u;
    }
}

// ---------------------------------------------------------------------------
// CSR build: counting sort of edges by dst. Payload packed as int2{src, ea}.
// ---------------------------------------------------------------------------
__global__ __launch_bounds__(256) void count_dst(
    const int* __restrict__ dst, int* __restrict__ cnt, int E)
{
    int i = blockIdx.x * 256 + threadIdx.x;
    const int stride = gridDim.x * 256;
    for (; i < E; i += stride) atomicAdd(&cnt[dst[i]], 1);
}

__device__ inline int wave_incl_scan(int v, int lane)
{
#pragma unroll
    for (int s = 1; s < 64; s <<= 1) {
        const int t = __shfl_up(v, s, 64);
        if (lane >= s) v += t;
    }
    return v;
}

// phase 1: per-block (1024 elems) exclusive scan + block total
__global__ __launch_bounds__(1024) void scan1(
    const int* __restrict__ cnt, int* __restrict__ off, int* __restrict__ bsum, int n)
{
    __shared__ int wsum[16];
    const int tid = threadIdx.x, lane = tid & 63, wid = tid >> 6;
    const int i = blockIdx.x * 1024 + tid;
    const int v = (i < n) ? cnt[i] : 0;
    const int incl = wave_incl_scan(v, lane);
    if (lane == 63) wsum[wid] = incl;
    __syncthreads();
    if (wid == 0) {
        int wv = (lane < 16) ? wsum[lane] : 0;
        wv = wave_incl_scan(wv, lane);
        if (lane < 16) wsum[lane] = wv;
    }
    __syncthreads();
    const int excl = (wid > 0 ? wsum[wid - 1] : 0) + incl - v;
    if (i < n) off[i] = excl;
    if (tid == 1023) bsum[blockIdx.x] = wsum[15];
}

// phase 2: scan the (<=64) block totals with one wave
__global__ __launch_bounds__(64) void scan2(int* __restrict__ bsum, int nb)
{
    const int lane = threadIdx.x;
    const int v = (lane < nb) ? bsum[lane] : 0;
    const int incl = wave_incl_scan(v, lane);
    if (lane < nb) bsum[lane] = incl - v;
}

// phase 3: add block offsets, copy to head, set off[n]
__global__ __launch_bounds__(1024) void scan3(
    int* __restrict__ off, int* __restrict__ head, const int* __restrict__ bsum,
    int n, int E)
{
    const int i = blockIdx.x * 1024 + threadIdx.x;
    if (i < n) {
        const int o = off[i] + bsum[blockIdx.x];
        off[i] = o; head[i] = o;
    } else if (i == n) {
        off[n] = E;
    }
}

__global__ __launch_bounds__(256) void fill_csr(
    const int* __restrict__ src, const int* __restrict__ dst,
    const float* __restrict__ ea, int* __restrict__ head,
    int2* __restrict__ edges, int E)
{
    int i = blockIdx.x * 256 + threadIdx.x;
    const int stride = gridDim.x * 256;
    for (; i < E; i += stride) {
        const int pos = atomicAdd(&head[dst[i]], 1);
        edges[pos] = make_int2(src[i], __float_as_int(ea[i]));
    }
}

// ---------------------------------------------------------------------------
// GINE aggregation (CSR): one wave per node, 2 cols/lane, fp16 gather operand.
// AFF=true: gathered rows (and residual) get BN scale/shift applied inline.
// acc[node] = res[node] + sum_p relu(xbn[src_p] + a_p*lw + lb)
// ---------------------------------------------------------------------------
template<bool AFF>
__global__ __launch_bounds__(256) void gine_aggr(
    const ushort* __restrict__ xh, const float* __restrict__ xres,
    const int* __restrict__ off, const int2* __restrict__ edges,
    const float* __restrict__ lw, const float* __restrict__ lb,
    const float* __restrict__ sc, const float* __restrict__ sh,
    float* __restrict__ acc, int N)
{
    const int lane = threadIdx.x & 63;
    const int node = blockIdx.x * 4 + (threadIdx.x >> 6);
    if (node >= N) return;
    const float2 lw2 = ((const float2*)lw)[lane];
    const float2 lb2 = ((const float2*)lb)[lane];
    float2 sc2, sh2;
    if constexpr (AFF) {
        sc2 = ((const float2*)sc)[lane];
        sh2 = ((const float2*)sh)[lane];
    }
    float2 s;
    if constexpr (AFF) {
        const uint u = ((const uint*)(xh + (size_t)node * 128))[lane];
        const float2 xv = h2f2(u);
        s.x = fmaf(xv.x, sc2.x, sh2.x);
        s.y = fmaf(xv.y, sc2.y, sh2.y);
    } else {
        s = ((const float2*)(xres + (size_t)node * 128))[lane];
    }
    const int pbeg = off[node], pend = off[node + 1];
#pragma unroll 2
    for (int p = pbeg; p < pend; ++p) {
        const int2 e = edges[p];
        const float a = __int_as_float(e.y);
        const uint u = ((const uint*)(xh + (size_t)e.x * 128))[lane];
        float2 xv = h2f2(u);
        if constexpr (AFF) { xv.x = fmaf(xv.x, sc2.x, sh2.x); xv.y = fmaf(xv.y, sc2.y, sh2.y); }
        s.x += fmaxf(fmaf(a, lw2.x, lb2.x) + xv.x, 0.f);
        s.y += fmaxf(fmaf(a, lw2.y, lb2.y) + xv.y, 0.f);
    }
    ((float2*)(acc + (size_t)node * 128))[lane] = s;
}

// ---------------------------------------------------------------------------
// Fused GEMM + bias + relu + BN-stats epilogue, optional input BN-affine.
// Y[n,m] = relu(sum_k Abn[n,k] W[k,m] + b[m]);  sum/sq accumulate column stats.
// A split at KS between A1 (opt fp16, opt affine sc1/sh1) and A2 (fp32, opt
// affine sc2/sh2). Y stored fp32 or fp16.
// ---------------------------------------------------------------------------
template<int K, int KS, int M, int BY, int TR, bool A1H, bool AFF1, bool AFF2, bool YH>
__global__ __launch_bounds__((M / 4) * BY) void gemm_rs(
    const void* __restrict__ A1v, const float* __restrict__ A2,
    const float* __restrict__ sc1, const float* __restrict__ sh1,
    const float* __restrict__ sc2, const float* __restrict__ sh2,
    const float* __restrict__ W, const float* __restrict__ bias,
    void* __restrict__ Yv, float* __restrict__ sum, float* __restrict__ sq, int N)
{
    constexpr int BX = M / 4;
    constexpr int NT = BX * BY;
    constexpr int R  = BY * TR;        // 64 rows per block
    constexpr int KC = 32;
    constexpr int AST = R + 4;
    __shared__ float Ws[KC * M];
    __shared__ float As[KC * AST];
    __shared__ float Red[2][BY][M];
    const int tx = threadIdx.x, ty = threadIdx.y;
    const int tid = ty * BX + tx;
    const int row0 = blockIdx.x * R;

    float acc[TR][4];
#pragma unroll
    for (int r = 0; r < TR; ++r) { acc[r][0] = acc[r][1] = acc[r][2] = acc[r][3] = 0.f; }

    for (int kc = 0; kc < K; kc += KC) {
        __syncthreads();
        for (int i = tid; i < KC * M / 4; i += NT)
            ((float4*)Ws)[i] = ((const float4*)(W + (size_t)kc * M))[i];
        for (int i = tid; i < R * KC / 4; i += NT) {
            const int r  = i / (KC / 4);
            const int k4 = i % (KC / 4);
            int row = row0 + r; if (row >= N) row = N - 1;   // clamp (stats/stores guarded)
            const int kg = kc + k4 * 4;
            float4 v;
            bool use2 = false;
            if constexpr (KS < K) use2 = (kg >= KS);
            if (use2) {
                const int kl = kg - KS;
                v = *(const float4*)(A2 + (size_t)row * (K - KS) + kl);
                if constexpr (AFF2) {
                    const float4 c = *(const float4*)(sc2 + kl);
                    const float4 d = *(const float4*)(sh2 + kl);
                    v.x = fmaf(v.x, c.x, d.x); v.y = fmaf(v.y, c.y, d.y);
                    v.z = fmaf(v.z, c.z, d.z); v.w = fmaf(v.w, c.w, d.w);
                }
            } else {
                if constexpr (A1H) {
                    const uint2 u = *(const uint2*)((const ushort*)A1v + (size_t)row * KS + kg);
                    const float2 f0 = h2f2(u.x), f1 = h2f2(u.y);
                    v.x = f0.x; v.y = f0.y; v.z = f1.x; v.w = f1.y;
                } else {
                    v = *(const float4*)((const float*)A1v + (size_t)row * KS + kg);
                }
                if constexpr (AFF1) {
                    const float4 c = *(const float4*)(sc1 + kg);
                    const float4 d = *(const float4*)(sh1 + kg);
                    v.x = fmaf(v.x, c.x, d.x); v.y = fmaf(v.y, c.y, d.y);
                    v.z = fmaf(v.z, c.z, d.z); v.w = fmaf(v.w, c.w, d.w);
                }
            }
            As[(k4 * 4 + 0) * AST + r] = v.x;
            As[(k4 * 4 + 1) * AST + r] = v.y;
            As[(k4 * 4 + 2) * AST + r] = v.z;
            As[(k4 * 4 + 3) * AST + r] = v.w;
        }
        __syncthreads();
#pragma unroll 8
        for (int kk = 0; kk < KC; ++kk) {
            const float4 w4 = *(const float4*)&Ws[kk * M + tx * 4];
            float a[TR];
            if constexpr (TR % 4 == 0) {
#pragma unroll
                for (int q = 0; q < TR / 4; ++q) {
                    const float4 av = *(const float4*)&As[kk * AST + ty * TR + q * 4];
                    a[q * 4 + 0] = av.x; a[q * 4 + 1] = av.y;
                    a[q * 4 + 2] = av.z; a[q * 4 + 3] = av.w;
                }
            } else {
#pragma unroll
                for (int r = 0; r < TR; ++r) a[r] = As[kk * AST + ty * TR + r];
            }
#pragma unroll
            for (int r = 0; r < TR; ++r) {
                acc[r][0] = fmaf(a[r], w4.x, acc[r][0]);
                acc[r][1] = fmaf(a[r], w4.y, acc[r][1]);
                acc[r][2] = fmaf(a[r], w4.z, acc[r][2]);
                acc[r][3] = fmaf(a[r], w4.w, acc[r][3]);
            }
        }
    }
    // epilogue: bias + relu + store + per-block column stats
    const float4 b4 = ((const float4*)bias)[tx];
    float s4[4] = {0.f, 0.f, 0.f, 0.f}, q4[4] = {0.f, 0.f, 0.f, 0.f};
#pragma unroll
    for (int r = 0; r < TR; ++r) {
        const int row = row0 + ty * TR + r;
        if (row < N) {
            const float o0 = fmaxf(acc[r][0] + b4.x, 0.f);
            const float o1 = fmaxf(acc[r][1] + b4.y, 0.f);
            const float o2 = fmaxf(acc[r][2] + b4.z, 0.f);
            const float o3 = fmaxf(acc[r][3] + b4.w, 0.f);
            if constexpr (YH) {
                ushort4 u;
                u.x = f2h(o0); u.y = f2h(o1); u.z = f2h(o2); u.w = f2h(o3);
                ((ushort4*)((ushort*)Yv + (size_t)row * M))[tx] = u;
            } else {
                float4 o; o.x = o0; o.y = o1; o.z = o2; o.w = o3;
                ((float4*)((float*)Yv + (size_t)row * M))[tx] = o;
            }
            s4[0] += o0; q4[0] = fmaf(o0, o0, q4[0]);
            s4[1] += o1; q4[1] = fmaf(o1, o1, q4[1]);
            s4[2] += o2; q4[2] = fmaf(o2, o2, q4[2]);
            s4[3] += o3; q4[3] = fmaf(o3, o3, q4[3]);
        }
    }
#pragma unroll
    for (int j = 0; j < 4; ++j) {
        Red[0][ty][tx * 4 + j] = s4[j];
        Red[1][ty][tx * 4 + j] = q4[j];
    }
    __syncthreads();
    if (tid < M) {
        float S = 0.f, Q = 0.f;
#pragma unroll 4
        for (int t = 0; t < BY; ++t) { S += Red[0][t][tid]; Q += Red[1][t][tid]; }
        unsafeAtomicAdd(&sum[tid], S);
        unsafeAtomicAdd(&sq[tid], Q);
    }
}

template<int M>
__global__ void bn_finalize(const float* __restrict__ sum, const float* __restrict__ sq,
                            const float* __restrict__ g, const float* __restrict__ be,
                            float* __restrict__ scale, float* __restrict__ shift, float invN)
{
    const int i = threadIdx.x;
    if (i < M) {
        const float m = sum[i] * invN;
        const float v = sq[i] * invN - m * m;
        const float sc = g[i] * rsqrtf(v + BN_EPS);
        scale[i] = sc;
        shift[i] = be[i] - m * sc;
    }
}

__global__ __launch_bounds__(256) void bn_apply_final(
    const float* __restrict__ Y16, const float* __restrict__ scale,
    const float* __restrict__ shift, float* __restrict__ out, int total)
{
    for (int i = blockIdx.x * 256 + threadIdx.x; i < total; i += gridDim.x * 256) {
        const int n = i / 10;
        const int c = i - n * 10;
        out[i] = fmaf(Y16[(size_t)n * 16 + c], scale[c], shift[c]);
    }
}

// pad w5 [96,10] -> [96,16], b5 [10] -> [16]
__global__ __launch_bounds__(256) void pad_w5(
    const float* __restrict__ w5, const float* __restrict__ b5,
    float* __restrict__ w5p, float* __restrict__ b5p)
{
    const int i = blockIdx.x * 256 + threadIdx.x;
    if (i < 96 * 16) {
        const int k = i >> 4, c = i & 15;
        w5p[i] = (c < 10) ? w5[k * 10 + c] : 0.f;
    } else if (i < 96 * 16 + 16) {
        const int c = i - 96 * 16;
        b5p[c] = (c < 10) ? b5[c] : 0.f;
    }
}

// ---------------------------------------------------------------------------
extern "C" void kernel_launch(void* const* d_in, const int* in_sizes, int n_in,
                              void* d_out, int out_size, void* d_ws, size_t ws_size,
                              hipStream_t stream)
{
    const float* x   = (const float*)d_in[0];
    const float* ea  = (const float*)d_in[1];
    const int*   ei  = (const int*)d_in[2];
    const float* lw  = (const float*)d_in[3];
    const float* lb  = (const float*)d_in[4];
    const float* w1  = (const float*)d_in[5];
    const float* b1  = (const float*)d_in[6];
    const float* g1  = (const float*)d_in[7];
    const float* be1 = (const float*)d_in[8];
    const float* w2  = (const float*)d_in[9];
    const float* b2  = (const float*)d_in[10];
    const float* g2  = (const float*)d_in[11];
    const float* be2 = (const float*)d_in[12];
    const float* w3  = (const float*)d_in[13];
    const float* b3  = (const float*)d_in[14];
    const float* g3  = (const float*)d_in[15];
    const float* be3 = (const float*)d_in[16];
    const float* w4  = (const float*)d_in[17];
    const float* b4  = (const float*)d_in[18];
    const float* g4  = (const float*)d_in[19];
    const float* be4 = (const float*)d_in[20];
    const float* w5  = (const float*)d_in[21];
    const float* b5  = (const float*)d_in[22];
    const float* g5  = (const float*)d_in[23];
    const float* be5 = (const float*)d_in[24];

    const int N = in_sizes[0] / 128;   // 50000
    const int E = in_sizes[1];         // 1600000
    const int* src = ei;
    const int* dst = ei + E;
    const float invN = 1.0f / (float)N;

    float*  ws    = (float*)d_ws;
    float*  bufA  = ws;                                 // N*128 f32 (t1,t2,y3,y5)
    ushort* h16   = (ushort*)(ws + (size_t)N * 128);    // N*128 fp16 (xh then y1h)
    float*  y2    = ws + (size_t)N * 192;               // N*64 f32
    float*  y4    = ws + (size_t)N * 128;               // N*96 f32 (overlaps h16+y2, both dead)
    float*  smallr = ws + (size_t)N * 256;
    float*  sums   = smallr;                            // 10 x 128 (sum_l, sq_l)
    float*  scales = smallr + 1280;
    float*  shifts = smallr + 1920;
    float*  w5p    = smallr + 2560;                     // 96*16
    float*  b5p    = w5p + 1536;
    int*    ibase  = (int*)(ws + (size_t)N * 256 + 8192);
    int*    cnt    = ibase;                             // 50048
    int*    off    = cnt + 50048;                       // 50064 (N+1 used)
    int*    head   = off + 50064;                       // 50048
    int*    bsum   = head + 50048;                      // 64
    int2*   edges  = (int2*)(bsum + 64);                // E
#define SUM(l)   (sums + (l) * 128)
#define SQ(l)    (sums + (5 + (l)) * 128)
#define SCALE(l) (scales + (l) * 128)
#define SHIFT(l) (shifts + (l) * 128)

    hipMemsetAsync(sums, 0, 1280 * sizeof(float), stream);
    hipMemsetAsync(cnt, 0, (size_t)N * sizeof(int), stream);
    pad_w5<<<7, 256, 0, stream>>>(w5, b5, w5p, b5p);
    cvt_f16<<<2048, 256, 0, stream>>>(x, h16, N * 32);

    // ---- CSR build (reused by both convs)
    const int nb = (N + 1023) / 1024;                   // 49
    count_dst<<<2048, 256, 0, stream>>>(dst, cnt, E);
    scan1<<<nb, 1024, 0, stream>>>(cnt, off, bsum, N);
    scan2<<<1, 64, 0, stream>>>(bsum, nb);
    scan3<<<nb, 1024, 0, stream>>>(off, head, bsum, N, E);
    fill_csr<<<2048, 256, 0, stream>>>(src, dst, ea, head, edges, E);

    const int gemmGrid = (N + 63) / 64;
    const int aggrGrid = (N + 3) / 4;

    // ---- conv1: t1 = x + sum relu(x[src]+e);  y1 = relu(t1@w1+b1) [fp16] + stats
    gine_aggr<false><<<aggrGrid, 256, 0, stream>>>(h16, x, off, edges, lw, lb, nullptr, nullptr, bufA, N);
    gemm_rs<128, 128, 128, 8, 8, false, false, false, true><<<gemmGrid, dim3(32, 8), 0, stream>>>(
        bufA, nullptr, nullptr, nullptr, nullptr, nullptr, w1, b1, h16, SUM(0), SQ(0), N);
    bn_finalize<128><<<1, 128, 0, stream>>>(SUM(0), SQ(0), g1, be1, SCALE(0), SHIFT(0), invN);

    // ---- conv2: t2 = bn(y1) + sum relu(bn(y1)[src]+e);  y2 = relu(t2@w2+b2) + stats
    gine_aggr<true><<<aggrGrid, 256, 0, stream>>>(h16, nullptr, off, edges, lw, lb, SCALE(0), SHIFT(0), bufA, N);
    gemm_rs<128, 128, 64, 16, 4, false, false, false, false><<<gemmGrid, dim3(16, 16), 0, stream>>>(
        bufA, nullptr, nullptr, nullptr, nullptr, nullptr, w2, b2, y2, SUM(1), SQ(1), N);
    bn_finalize<64><<<1, 128, 0, stream>>>(SUM(1), SQ(1), g2, be2, SCALE(1), SHIFT(1), invN);

    // ---- lin1: y3 = relu(concat(bn(y1), bn(y2)) @ w3 + b3) + stats
    gemm_rs<192, 128, 96, 8, 8, true, true, true, false><<<gemmGrid, dim3(24, 8), 0, stream>>>(
        h16, y2, SCALE(0), SHIFT(0), SCALE(1), SHIFT(1), w3, b3, bufA, SUM(2), SQ(2), N);
    bn_finalize<96><<<1, 128, 0, stream>>>(SUM(2), SQ(2), g3, be3, SCALE(2), SHIFT(2), invN);

    // ---- mlp1 layer 1: y4 = relu(bn(y3) @ w4 + b4) + stats
    gemm_rs<96, 96, 96, 8, 8, false, true, false, false><<<gemmGrid, dim3(24, 8), 0, stream>>>(
        bufA, nullptr, SCALE(2), SHIFT(2), nullptr, nullptr, w4, b4, y4, SUM(3), SQ(3), N);
    bn_finalize<96><<<1, 128, 0, stream>>>(SUM(3), SQ(3), g4, be4, SCALE(3), SHIFT(3), invN);

    // ---- mlp1 layer 2: y5 = relu(bn(y4) @ w5p + b5p) [N,16] + stats
    gemm_rs<96, 96, 16, 64, 1, false, true, false, false><<<gemmGrid, dim3(4, 64), 0, stream>>>(
        y4, nullptr, SCALE(3), SHIFT(3), nullptr, nullptr, w5p, b5p, bufA, SUM(4), SQ(4), N);
    bn_finalize<10><<<1, 128, 0, stream>>>(SUM(4), SQ(4), g5, be5, SCALE(4), SHIFT(4), invN);

    // ---- final BN apply -> out [N,10]
    bn_apply_final<<<1024, 256, 0, stream>>>(bufA, SCALE(4), SHIFT(4), (float*)d_out, N * 10);
#undef SUM
#undef SQ
#undef SCALE
#undef SHIFT
}